// Round 3
// baseline (602.061 us; speedup 1.0000x reference)
//
#include <hip/hip_runtime.h>
#include <cfloat>
#include <cmath>

#define V 128000
#define B 256
#define L 256
#define NB 21
#define CAPV 4096      // candidate capacity
#define CAPL 3840      // floor-selection bound (CAPV - 256 pen-append headroom)
#define NSMALL 1024    // O(n^2) exact paths below this; bisection above
static constexpr float EPSF = 1e-5f;

// ---------------- Threefry-2x32-20, JAX partitionable mode ----------------
__device__ __forceinline__ unsigned rotl32(unsigned x, int r) {
  return (x << r) | (x >> (32 - r));
}
__device__ __forceinline__ unsigned tf_bits(unsigned e) {
  const unsigned k0 = 0u, k1 = 42u;
  const unsigned k2 = k0 ^ k1 ^ 0x1BD11BDAu;
  unsigned x0 = 0u + k0;
  unsigned x1 = e + k1;
#define TF_RND(r) { x0 += x1; x1 = rotl32(x1, r); x1 ^= x0; }
  TF_RND(13) TF_RND(15) TF_RND(26) TF_RND(6)
  x0 += k1; x1 += k2 + 1u;
  TF_RND(17) TF_RND(29) TF_RND(16) TF_RND(24)
  x0 += k2; x1 += k0 + 2u;
  TF_RND(13) TF_RND(15) TF_RND(26) TF_RND(6)
  x0 += k0; x1 += k1 + 3u;
  TF_RND(17) TF_RND(29) TF_RND(16) TF_RND(24)
  x0 += k1; x1 += k2 + 4u;
  TF_RND(13) TF_RND(15) TF_RND(26) TF_RND(6)
  x0 += k2; x1 += k0 + 5u;
#undef TF_RND
  return x0 ^ x1;
}
__device__ __forceinline__ float gumbelf(unsigned e) {
  unsigned bits = tf_bits(e);
  float f = __uint_as_float((bits >> 9) | 0x3F800000u) - 1.0f;   // [0,1)
  float u = f + 1e-10f;      // (1.0f - 1e-10f) rounds to 1.0f -> no multiply
  u = fmaxf(u, 1e-10f);
  return -logf(-logf(u));
}

// order-preserving float->uint key
__device__ __forceinline__ unsigned flipkey(float v) {
  unsigned u = __float_as_uint(v);
  return (u & 0x80000000u) ? ~u : (u | 0x80000000u);
}
__device__ __forceinline__ float unflip(unsigned k) {
  return __uint_as_float((k & 0x80000000u) ? (k ^ 0x80000000u) : ~k);
}

// exact v for token idx: penalized override else raw/T (IEEE division)
__device__ __forceinline__ float probe_v(const int* hk, const float* hv,
                                         int idx, float raw, float T) {
  float v = raw / T;
  unsigned h = ((unsigned)idx * 2654435761u) >> 22;
  for (;;) {
    int k = hk[h];
    if (k == idx) { v = hv[h]; break; }
    if (k == -1) break;
    h = (h + 1) & 1023u;
  }
  return v;
}

// ---------------- LDS layout (dynamic, byte offsets) ----------------------
#define OFF_HCNT 0         // u32[4096] count hist -> desc-incl prefix
#define OFF_HSUM 16384     // f32[4096] expsum hist (K==0) -> prefix; scratch later
#define OFF_LRAW 32768     // f32[CAPV] candidate raw values (also ids[256] early)
#define OFF_LI   49152     // i32[CAPV] candidate indices
#define OFF_LV   65536     // f32[CAPV] candidate v values
#define OFF_LE   81920     // f32[CAPV] candidate exp(v)
#define OFF_HK   98304     // i32[1024] hash keys (penalized ids)
#define OFF_HV   102400    // f32[1024] hash vals (penalized v)
#define OFF_STG  106496    // 128B reduce/scan staging
#define OFF_SCL  106624    // scalars
#define SMEM_SZ  106688

struct Scal {
  double A0;
  int pc, f, f0, f21, bstar, b2, nv, n2, qn, mode, floorV;
  float kth;
};

// ---------------- block reduce helpers ------------------------------------
__device__ __forceinline__ double bredd(double x, void* stg, int t) {
  double* s = (double*)stg;
  for (int o = 32; o; o >>= 1) x += __shfl_down(x, o, 64);
  if ((t & 63) == 0) s[t >> 6] = x;
  __syncthreads();
  if (t < 64) {
    double y = (t < 16) ? s[t] : 0.0;
    for (int o = 8; o; o >>= 1) y += __shfl_down(y, o, 64);
    if (t == 0) s[0] = y;
  }
  __syncthreads();
  double r = s[0];
  __syncthreads();
  return r;
}
__device__ __forceinline__ float bredminf(float x, void* stg, int t) {
  float* s = (float*)stg;
  for (int o = 32; o; o >>= 1) x = fminf(x, __shfl_down(x, o, 64));
  if ((t & 63) == 0) s[t >> 6] = x;
  __syncthreads();
  if (t < 64) {
    float y = (t < 16) ? s[t] : FLT_MAX;
    for (int o = 8; o; o >>= 1) y = fminf(y, __shfl_down(y, o, 64));
    if (t == 0) s[0] = y;
  }
  __syncthreads();
  float r = s[0];
  __syncthreads();
  return r;
}
__device__ __forceinline__ void bredargmax(float v, int i, void* stg, int t,
                                           float& ov, int& oi) {
  float* sv = (float*)stg; int* si = (int*)stg + 16;
  for (int o = 32; o; o >>= 1) {
    float v2 = __shfl_down(v, o, 64); int i2 = __shfl_down(i, o, 64);
    if (v2 > v || (v2 == v && i2 < i)) { v = v2; i = i2; }
  }
  if ((t & 63) == 0) { sv[t >> 6] = v; si[t >> 6] = i; }
  __syncthreads();
  if (t < 64) {
    float y; int yi;
    if (t < 16) { y = sv[t]; yi = si[t]; } else { y = -FLT_MAX; yi = 0x7FFFFFFF; }
    for (int o = 8; o; o >>= 1) {
      float v2 = __shfl_down(y, o, 64); int i2 = __shfl_down(yi, o, 64);
      if (v2 > y || (v2 == y && i2 < yi)) { y = v2; yi = i2; }
    }
    if (t == 0) { sv[0] = y; si[0] = yi; }
  }
  __syncthreads();
  ov = sv[0]; oi = si[0];
  __syncthreads();
}

// in-place descending inclusive prefix: arr[b] = sum_{b' >= b} arr[b']
template <typename T>
__device__ __forceinline__ void scan_desc(T* arr, int nbins, void* stg, int t) {
  T* s = (T*)stg;
  T carry = (T)0;
  for (int base = nbins - 1024; base >= 0; base -= 1024) {
    int bin = base + 1023 - t;
    T x = arr[bin];
    for (int o = 1; o < 64; o <<= 1) {
      T y = __shfl_up(x, o, 64);
      if ((t & 63) >= o) x += y;
    }
    if ((t & 63) == 63) s[t >> 6] = x;
    __syncthreads();
    if (t < 64) {
      T y = (t < 16) ? s[t] : (T)0;
      for (int o = 1; o < 16; o <<= 1) {
        T z = __shfl_up(y, o, 64);
        if (t >= o) y += z;
      }
      if (t < 16) s[t] = y;
    }
    __syncthreads();
    T add = (t >= 64) ? s[(t >> 6) - 1] : (T)0;
    arr[bin] = x + add + carry;
    carry = carry + s[15];
    __syncthreads();
  }
}

// ---------------- fused sampler -------------------------------------------
__global__ void __launch_bounds__(1024)
k_fused(const float* __restrict__ logits, const float* __restrict__ temp,
        const int* __restrict__ topk, const float* __restrict__ topp,
        const float* __restrict__ rep, const float* __restrict__ freq,
        const float* __restrict__ pres, const int* __restrict__ oids,
        float* __restrict__ out)
{
  extern __shared__ char smem[];
  unsigned* hcnt = (unsigned*)(smem + OFF_HCNT);
  float*    hsum = (float*)(smem + OFF_HSUM);
  float*    lraw = (float*)(smem + OFF_LRAW);
  int*      li   = (int*)(smem + OFF_LI);
  float*    lv   = (float*)(smem + OFF_LV);
  float*    le   = (float*)(smem + OFF_LE);
  int*      hk   = (int*)(smem + OFF_HK);
  float*    hv   = (float*)(smem + OFF_HV);
  void*     stg  = (void*)(smem + OFF_STG);
  Scal*     sc   = (Scal*)(smem + OFF_SCL);

  const int r = blockIdx.x, t = threadIdx.x;
  const float* row = logits + (size_t)r * V;
  const float Traw = temp[r];
  const float T = (Traw < EPSF) ? 1.0f : Traw;
  const int K = topk[r];
  const bool hasK = (K > 0);
  const int keff = hasK ? min(K, V) : V;
  const float tp = topp[r];
  const unsigned ebase = (unsigned)r * (unsigned)V;

  // ---- init
  for (int i = t; i < 4096; i += 1024) { hcnt[i] = 0u; hsum[i] = 0.f; }
  hk[t] = -1;
  if (t == 0) {
    sc->A0 = 0.0; sc->pc = 0; sc->f = 4095; sc->f0 = -1; sc->f21 = 4095;
    sc->bstar = 4095; sc->b2 = -1; sc->nv = 0; sc->n2 = 0; sc->qn = 0;
    sc->mode = 0; sc->floorV = 0; sc->kth = -FLT_MAX;
  }
  int* ids = (int*)lraw;                  // reuse candidate array early
  if (t < L) ids[t] = oids[r * L + t];
  __syncthreads();

  // ---- inline penalty: dedup output tokens, exact penalized v into hash
  if (t < L) {
    const int my = ids[t];
    int c = 0, firstpos = t;
    for (int j = 0; j < L; ++j) {
      int o = ids[j];
      if (o == my) { c++; if (j < firstpos) firstpos = j; }
    }
    if (firstpos == t) {                  // one writer per unique token
      float x = row[my];
      float rp = rep[r];
      x = (x > 0.f) ? (x / rp) : (x * rp);
      x = __fsub_rn(x, __fmul_rn((float)c, freq[r]));
      x = __fsub_rn(x, pres[r]);
      x = x / T;
      unsigned h = ((unsigned)my * 2654435761u) >> 22;
      while (atomicCAS(&hk[h], -1, my) != -1) h = (h + 1) & 1023u;
      hv[h] = x;
      atomicAdd(&sc->pc, 1);
    }
  }
  __syncthreads();
  const int pc = sc->pc;

  // ---- pass A: raw-keyed histogram + raw lse (heavy exact path only if K==0)
  double dacc = 0.0, sacc = 0.0;
  if (hasK) {
    for (int i4 = t; i4 < V / 4; i4 += 1024) {
      const float4 x = reinterpret_cast<const float4*>(row)[i4];
      const float vs[4] = {x.x, x.y, x.z, x.w};
#pragma unroll
      for (int c = 0; c < 4; ++c) {
        float raw = vs[c];
        atomicAdd(&hcnt[flipkey(raw) >> 20], 1u);
        dacc += (double)expf(raw);
      }
    }
  } else {
    for (int i4 = t; i4 < V / 4; i4 += 1024) {
      const float4 x = reinterpret_cast<const float4*>(row)[i4];
      const float vs[4] = {x.x, x.y, x.z, x.w};
#pragma unroll
      for (int c = 0; c < 4; ++c) {
        float raw = vs[c]; int idx = i4 * 4 + c;
        float v = probe_v(hk, hv, idx, raw, T);
        unsigned fk = flipkey(v);
        atomicAdd(&hcnt[fk >> 20], 1u);
        float ev = expf(v);
        atomicAdd(&hsum[fk >> 20], ev);
        sacc += (double)ev;
        dacc += (double)expf(raw);
      }
    }
  }
  __syncthreads();
  const float lseF = (float)log(bredd(dacc, stg, t));
  const double Sall = hasK ? 0.0 : bredd(sacc, stg, t);

  // ---- descending inclusive prefixes
  scan_desc<unsigned>(hcnt, 4096, stg, t);
  if (!hasK) scan_desc<float>(hsum, 4096, stg, t);

  // ---- crossing-bin finds (unique-writer parallel searches)
  for (int b = t; b < 4096; b += 1024) {
    unsigned incl = hcnt[b];
    unsigned below = (b > 0) ? hcnt[b - 1] : 0xFFFFFFFFu;
    if (incl <= (unsigned)CAPL && below > (unsigned)CAPL) sc->bstar = b;
  }
  if (hasK) {
    const unsigned NEED = (unsigned)(keff + pc + 29);
    for (int b = t; b < 4096; b += 1024) {
      unsigned incl = hcnt[b]; unsigned abv = (b < 4095) ? hcnt[b + 1] : 0u;
      if (incl >= NEED && abv < NEED) sc->f = b;
    }
  } else {
    const unsigned NEED2 = (unsigned)(21 + pc + 8);
    for (int b = t; b < 4096; b += 1024) {
      unsigned incl = hcnt[b]; unsigned abv = (b < 4095) ? hcnt[b + 1] : 0u;
      if (incl >= NEED2 && abv < NEED2) sc->f21 = b;
    }
    const double PS0 = (double)tp * Sall;
    for (int b = t; b < 4096; b += 1024) {
      double incl = (double)hsum[b];
      double abv = (b < 4095) ? (double)hsum[b + 1] : 0.0;
      if (abv < PS0 && PS0 <= incl) sc->f0 = b;
    }
  }
  __syncthreads();

  // ---- floor/mode select (t==0, uniform)
  if (t == 0) {
    if (hasK) {
      int f = sc->f;
      sc->mode = 0;
      sc->floorV = (hcnt[f] <= (unsigned)CAPV) ? f : sc->bstar;  // degrade: freak
    } else {
      int f0 = sc->f0;
      if (f0 < 0) { sc->mode = 2; sc->floorV = sc->bstar; }
      else {
        sc->A0 = (f0 < 4095) ? (double)hsum[f0 + 1] : 0.0;
        int f21 = sc->f21;
        int fm = min(max(f0 - 1, 0), f21);
        int fb = min(f0, f21);
        if (hcnt[fm] <= (unsigned)CAPL) { sc->mode = 0; sc->floorV = fm; }
        else if (hcnt[fb] <= (unsigned)CAPL) { sc->mode = 0; sc->floorV = fb; }
        else { sc->mode = 1; sc->floorV = sc->bstar; }
      }
    }
  }
  __syncthreads();
  const int mode = sc->mode;
  const int floorV = sc->floorV;

  // ---- pass B: collect candidates (raw keys for hasK, v keys for K==0)
  if (hasK) {
    for (int i4 = t; i4 < V / 4; i4 += 1024) {
      const float4 x = reinterpret_cast<const float4*>(row)[i4];
      const float vs[4] = {x.x, x.y, x.z, x.w};
#pragma unroll
      for (int c = 0; c < 4; ++c) {
        float raw = vs[c];
        if ((int)(flipkey(raw) >> 20) >= floorV) {
          int p = atomicAdd(&sc->nv, 1);
          if (p < CAPV) { lraw[p] = raw; li[p] = i4 * 4 + c; }
        }
      }
    }
  } else {
    for (int i4 = t; i4 < V / 4; i4 += 1024) {
      const float4 x = reinterpret_cast<const float4*>(row)[i4];
      const float vs[4] = {x.x, x.y, x.z, x.w};
#pragma unroll
      for (int c = 0; c < 4; ++c) {
        float raw = vs[c]; int idx = i4 * 4 + c;
        float v = probe_v(hk, hv, idx, raw, T);
        if ((int)(flipkey(v) >> 20) >= floorV) {
          int p = atomicAdd(&sc->nv, 1);
          if (p < CAPV) { lraw[p] = raw; li[p] = idx; }
        }
      }
    }
  }
  __syncthreads();
  const int n = min(sc->nv, CAPV);

  // ---- K==0: union in penalized tokens not collected (raw-top-20 exactness)
  if (!hasK) {
    int id = hk[t];
    if (id >= 0) {
      float vpen = hv[t];
      if ((int)(flipkey(vpen) >> 20) < floorV) {
        float raw = row[id];
        int p = n + atomicAdd(&sc->n2, 1);
        if (p < CAPV) { lraw[p] = raw; li[p] = id; }
      }
    }
  }
  __syncthreads();
  const int ntop = hasK ? n : min(n + sc->n2, CAPV);

  // ---- candidate prep: exact v and exp(v)
  for (int j = t; j < n; j += 1024) {
    float v = probe_v(hk, hv, li[j], lraw[j], T);
    lv[j] = v; le[j] = expf(v);
  }
  __syncthreads();

  // ---- greedy argmax over candidates (contains the global v-max)
  float mg = -FLT_MAX; int mgi = 0x7FFFFFFF;
  for (int j = t; j < n; j += 1024) {
    float xj = lv[j]; int ij = li[j];
    if (xj > mg || (xj == mg && ij < mgi)) { mg = xj; mgi = ij; }
  }
  float gv; int gi;
  bredargmax(mg, mgi, stg, t, gv, gi);

  // ---- raw top-20 + logprob cols 1..20
  if (t < 20) {
    out[B + r * NB + 1 + t] = -INFINITY;
    out[B + B * NB + r * NB + 1 + t] = 0.f;
  }
  __syncthreads();
  if (ntop <= NSMALL) {
    for (int j = t; j < ntop; j += 1024) {
      float xj = lraw[j]; int ij = li[j];
      int rank = 0;
      for (int i = 0; i < ntop; ++i) {
        float xi = lraw[i]; int ii = li[i];
        rank += (xi > xj || (xi == xj && ii < ij)) ? 1 : 0;
      }
      if (rank < 20) {
        out[B + r * NB + 1 + rank] = xj - lseF;
        out[B + B * NB + r * NB + 1 + rank] = (float)ij;
      }
    }
  } else {
    // bisect the 21st raw key, then wave-parallel rank-count for qualifiers
    unsigned lo = 0u, hi = 0xFFFFFFFFu;
    while (lo < hi) {
      unsigned mid = lo + ((hi - lo) >> 1) + 1u;
      double part = 0.0;
      for (int j = t; j < ntop; j += 1024)
        part += (flipkey(lraw[j]) >= mid) ? 1.0 : 0.0;
      double cnt = bredd(part, stg, t);
      if (cnt >= 21.0) lo = mid; else hi = mid - 1u;
    }
    float* qraw = hsum; int* qidx = (int*)hsum + 64;   // hsum scratch (A0 saved)
    for (int j = t; j < ntop; j += 1024)
      if (flipkey(lraw[j]) >= lo) {
        int p = atomicAdd(&sc->qn, 1);
        if (p < 64) { qraw[p] = lraw[j]; qidx[p] = li[j]; }
      }
    __syncthreads();
    const int qn = min(sc->qn, 64);
    const int w = t >> 6, lane = t & 63;
    for (int q = w; q < qn; q += 16) {
      float rq = qraw[q]; int iq = qidx[q];
      int cnt = 0;
      for (int i = lane; i < ntop; i += 64) {
        float xi = lraw[i]; int ii = li[i];
        cnt += (xi > rq || (xi == rq && ii < iq)) ? 1 : 0;
      }
      for (int o = 32; o; o >>= 1) cnt += __shfl_down(cnt, o, 64);
      if (lane == 0 && cnt < 20) {
        out[B + r * NB + 1 + cnt] = rq - lseF;
        out[B + B * NB + r * NB + 1 + cnt] = (float)iq;
      }
    }
  }
  __syncthreads();

  // ---- exact kth (K>0) and survivor mass S
  float kth = -FLT_MAX;
  double S;
  if (hasK) {
    if (n <= NSMALL) {
      for (int j = t; j < n; j += 1024) {
        float xj = lv[j];
        int g = 0, e = 0;
        for (int i = 0; i < n; ++i) { float xi = lv[i]; g += (xi > xj); e += (xi == xj); }
        if (g < keff && keff <= g + e) sc->kth = xj;
      }
      __syncthreads();
    } else {
      unsigned lo = 0u, hi = 0xFFFFFFFFu;
      while (lo < hi) {
        unsigned mid = lo + ((hi - lo) >> 1) + 1u;
        double part = 0.0;
        for (int j = t; j < n; j += 1024) part += (flipkey(lv[j]) >= mid) ? 1.0 : 0.0;
        double C = bredd(part, stg, t);
        if (C >= (double)keff) lo = mid; else hi = mid - 1u;
      }
      float cand = FLT_MAX;
      for (int j = t; j < n; j += 1024) if (flipkey(lv[j]) >= lo) cand = fminf(cand, lv[j]);
      float kk = bredminf(cand, stg, t);
      if (t == 0 && kk != FLT_MAX) sc->kth = kk;
      __syncthreads();
    }
    kth = sc->kth;
    double part = 0.0;
    for (int j = t; j < n; j += 1024) if (lv[j] >= kth) part += (double)le[j];
    S = bredd(part, stg, t);
  } else {
    S = Sall;
  }
  const double PS = (double)tp * S;

  // ---- top-p threshold: thr = min{x >= kth : sum_{w > x} e^w < PS}
  float thr;
  if (mode == 0) {
    if (n <= NSMALL) {
      float cand = FLT_MAX;
      for (int j = t; j < n; j += 1024) {
        float xj = lv[j];
        if (xj < kth) continue;
        double G = 0.0;
        for (int i = 0; i < n; ++i) { float xi = lv[i]; if (xi > xj) G += (double)le[i]; }
        if (G < PS) cand = fminf(cand, xj);
      }
      thr = bredminf(cand, stg, t);
      if (thr == FLT_MAX) thr = kth;
    } else {
      unsigned lo = hasK ? flipkey(kth) : ((unsigned)floorV << 20);
      unsigned hi = 0xFFFFFFFFu;
      while (lo < hi) {
        unsigned mid = lo + ((hi - lo) >> 1);
        double part = 0.0;
        for (int j = t; j < n; j += 1024)
          if (flipkey(lv[j]) > mid) part += (double)le[j];
        double G = bredd(part, stg, t);
        if (G < PS) hi = mid; else lo = mid + 1u;
      }
      float cand = FLT_MAX;
      for (int j = t; j < n; j += 1024) if (flipkey(lv[j]) >= lo) cand = fminf(cand, lv[j]);
      thr = bredminf(cand, stg, t);
      if (thr == FLT_MAX) thr = kth;
    }
  } else if (mode == 1) {
    // K==0 fat row: 12-bit sub-histogram of mass-crossing bin, exact inside
    const int bp0 = sc->f0;
    float* sub = (float*)hcnt;                    // hcnt prefix no longer needed
    for (int i = t; i < 4096; i += 1024) sub[i] = 0.f;
    if (t == 0) sc->n2 = 0;
    __syncthreads();
    for (int i4 = t; i4 < V / 4; i4 += 1024) {
      const float4 x = reinterpret_cast<const float4*>(row)[i4];
      const float vs[4] = {x.x, x.y, x.z, x.w};
#pragma unroll
      for (int c = 0; c < 4; ++c) {
        float raw = vs[c]; int idx = i4 * 4 + c;
        float v = probe_v(hk, hv, idx, raw, T);
        unsigned fk = flipkey(v);
        if ((int)(fk >> 20) == bp0) atomicAdd(&sub[(fk >> 8) & 0xFFFu], expf(v));
      }
    }
    __syncthreads();
    scan_desc<float>(sub, 4096, stg, t);
    const double A0 = sc->A0;
    for (int s2 = t; s2 < 4096; s2 += 1024) {
      double incl = A0 + (double)sub[s2];
      double abv = A0 + ((s2 < 4095) ? (double)sub[s2 + 1] : 0.0);
      if (abv < PS && PS <= incl) sc->b2 = s2;
    }
    __syncthreads();
    const int b2 = sc->b2;
    if (b2 < 0) {
      thr = unflip((unsigned)bp0 << 20);
    } else {
      const double A2 = A0 + ((b2 < 4095) ? (double)sub[b2 + 1] : 0.0);
      for (int i4 = t; i4 < V / 4; i4 += 1024) {
        const float4 x = reinterpret_cast<const float4*>(row)[i4];
        const float vs[4] = {x.x, x.y, x.z, x.w};
#pragma unroll
        for (int c = 0; c < 4; ++c) {
          float raw = vs[c]; int idx = i4 * 4 + c;
          float v = probe_v(hk, hv, idx, raw, T);
          unsigned fk = flipkey(v);
          if ((int)(fk >> 20) == bp0 && (int)((fk >> 8) & 0xFFFu) == b2) {
            int p = atomicAdd(&sc->n2, 1);
            if (p < CAPV) { lv[p] = v; le[p] = expf(v); }
          }
        }
      }
      __syncthreads();
      const int n2 = min(sc->n2, CAPV);
      float cand = FLT_MAX;
      for (int j = t; j < n2; j += 1024) {
        float xj = lv[j];
        double G = A2;
        for (int i = 0; i < n2; ++i) { float xi = lv[i]; if (xi > xj) G += (double)le[i]; }
        if (G < PS) cand = fminf(cand, xj);
      }
      thr = bredminf(cand, stg, t);
      if (thr == FLT_MAX)
        thr = unflip(((unsigned)bp0 << 20) | ((unsigned)(b2 + 1) << 8));
    }
  } else {
    thr = -FLT_MAX;                               // mode 2: everything survives
  }

  // ---- gumbel argmax over survivors (v >= thr)
  float yv = -FLT_MAX; int yi = 0x7FFFFFFF;
  if (mode == 0) {
    for (int j = t; j < n; j += 1024) {
      float xj = lv[j];
      if (xj >= thr) {
        int ij = li[j];
        float y = xj + gumbelf(ebase + (unsigned)ij);
        if (y > yv || (y == yv && ij < yi)) { yv = y; yi = ij; }
      }
    }
  } else {
    for (int i4 = t; i4 < V / 4; i4 += 1024) {    // rare K==0 fat rows
      const float4 x = reinterpret_cast<const float4*>(row)[i4];
      const float vs[4] = {x.x, x.y, x.z, x.w};
#pragma unroll
      for (int c = 0; c < 4; ++c) {
        float raw = vs[c]; int idx = i4 * 4 + c;
        float v = probe_v(hk, hv, idx, raw, T);
        if (v >= thr) {
          float y = v + gumbelf(ebase + (unsigned)idx);
          if (y > yv || (y == yv && idx < yi)) { yv = y; yi = idx; }
        }
      }
    }
  }
  float fy; int fyi;
  bredargmax(yv, yi, stg, t, fy, fyi);

  if (t == 0) {
    const int samp = (Traw < EPSF) ? gi : fyi;
    out[r] = (float)samp;                         // sampled_token_ids
    out[B + r * NB] = row[samp] - lseF;           // logprobs col 0
    out[B + B * NB + r * NB] = (float)samp;       // indices col 0
  }
}

// ---------------- launch ---------------------------------------------------
extern "C" void kernel_launch(void* const* d_in, const int* in_sizes, int n_in,
                              void* d_out, int out_size, void* d_ws, size_t ws_size,
                              hipStream_t stream) {
  const float* logits = (const float*)d_in[0];
  const float* temp   = (const float*)d_in[1];
  const int*   tkp    = (const int*)d_in[2];
  const float* tpp    = (const float*)d_in[3];
  const float* rep    = (const float*)d_in[4];
  const float* freq   = (const float*)d_in[5];
  const float* pres   = (const float*)d_in[6];
  const int*   oids   = (const int*)d_in[7];
  float* out = (float*)d_out;

  (void)hipFuncSetAttribute((const void*)k_fused,
                            hipFuncAttributeMaxDynamicSharedMemorySize, SMEM_SZ);

  k_fused<<<B, 1024, SMEM_SZ, stream>>>(logits, temp, tkp, tpp,
                                        rep, freq, pres, oids, out);
}